// Round 18
// baseline (590.283 us; speedup 1.0000x reference)
//
#include <hip/hip_runtime.h>
#include <hip/hip_bf16.h>

#define DM 1024
#define NH 16
#define DK 64
#define TT 2048
#define NBATCH 4
#define BT 8192   // NBATCH*TT

typedef __attribute__((ext_vector_type(8))) short short8;
typedef __attribute__((ext_vector_type(4))) float f32x4;
typedef unsigned short u16;

#define MFMA(a,b,c) __builtin_amdgcn_mfma_f32_16x16x32_bf16((a),(b),(c),0,0,0)

// 1/sqrt(64) * log2(e): folded into Q so attn softmax can use exp2 directly
#define QSCALE 0.18033688011112684f

// raw v_exp_f32 (flush-denorm fine for softmax), skips OCML fixup code
#define EXP2(x) __builtin_amdgcn_exp2f(x)

__device__ __forceinline__ u16 f2bf(float f){
  union { float f; unsigned u; } v; v.f = f;
  return (u16)((v.u + 0x7fffu + ((v.u >> 16) & 1u)) >> 16);
}

__device__ __forceinline__ unsigned cvtpk(float lo, float hi){
  unsigned r;
  asm("v_cvt_pk_bf16_f32 %0, %1, %2" : "=v"(r) : "v"(lo), "v"(hi));
  return r;
}

// async global->LDS DMA, 16B/lane. LDS dest must be wave-uniform base (+lane*16).
__device__ __forceinline__ void gload16(const void* g, void* l){
  __builtin_amdgcn_global_load_lds((__attribute__((address_space(1))) void*)(g),
                                   (__attribute__((address_space(3))) void*)(l), 16, 0, 0);
}

// cross-lane reduce over the 4 16-lane groups (lane ^16, ^32): pure-VALU permlanes
__device__ __forceinline__ float plmax(float x){
#if __has_builtin(__builtin_amdgcn_permlane16_swap) && __has_builtin(__builtin_amdgcn_permlane32_swap)
  auto r = __builtin_amdgcn_permlane16_swap(__float_as_uint(x), __float_as_uint(x), false, false);
  x = fmaxf(__uint_as_float(r[0]), __uint_as_float(r[1]));
  auto r2 = __builtin_amdgcn_permlane32_swap(__float_as_uint(x), __float_as_uint(x), false, false);
  x = fmaxf(__uint_as_float(r2[0]), __uint_as_float(r2[1]));
#else
  x = fmaxf(x, __shfl_xor(x, 16, 64));
  x = fmaxf(x, __shfl_xor(x, 32, 64));
#endif
  return x;
}

__device__ __forceinline__ float plsum(float x){
#if __has_builtin(__builtin_amdgcn_permlane16_swap) && __has_builtin(__builtin_amdgcn_permlane32_swap)
  auto r = __builtin_amdgcn_permlane16_swap(__float_as_uint(x), __float_as_uint(x), false, false);
  x = __uint_as_float(r[0]) + __uint_as_float(r[1]);
  auto r2 = __builtin_amdgcn_permlane32_swap(__float_as_uint(x), __float_as_uint(x), false, false);
  x = __uint_as_float(r2[0]) + __uint_as_float(r2[1]);
#else
  x = x + __shfl_xor(x, 16, 64);
  x = x + __shfl_xor(x, 32, 64);
#endif
  return x;
}

// ---------------- prep: x fp32->bf16  +  W (K,N) fp32 -> wt (N,K) bf16 ----------------
// merged single launch (block-uniform branch): blocks [0,8192) convert x,
// blocks [8192, 8192+3072) transpose+convert the three weight matrices.
__global__ __launch_bounds__(256) void prep(
    const float* __restrict__ x, u16* __restrict__ xb,
    const float* __restrict__ Wq, const float* __restrict__ Wk, const float* __restrict__ Wv,
    u16* __restrict__ wtq, u16* __restrict__ wtk, u16* __restrict__ wtv){
  __shared__ float tile[32][33];
  const int id = blockIdx.x;
  if(id < 8192){
    int i = (id * 256 + threadIdx.x) * 4;
    float4 v = *(const float4*)(x + i);
    ushort4 o; o.x = f2bf(v.x); o.y = f2bf(v.y); o.z = f2bf(v.z); o.w = f2bf(v.w);
    *(ushort4*)(xb + i) = o;
  } else {
    int r3 = id - 8192;                 // 0..3071
    int z = r3 >> 10;                   // 0..2
    int rem = r3 & 1023;
    int bx = rem & 31, by = rem >> 5;
    const float* W = (z == 0) ? Wq : (z == 1) ? Wk : Wv;
    u16* wt = (z == 0) ? wtq : (z == 1) ? wtk : wtv;
    int k0 = bx * 32, n0 = by * 32;
    int tx = threadIdx.x & 31, ty = threadIdx.x >> 5;
    #pragma unroll
    for(int r = ty; r < 32; r += 8)
      tile[r][tx] = W[(size_t)(k0 + r) * DM + n0 + tx];
    __syncthreads();
    #pragma unroll
    for(int r = ty; r < 32; r += 8)
      wt[(size_t)(n0 + r) * DM + k0 + tx] = f2bf(tile[tx][r]);
  }
}

// ---------------- FUSED QKV projection GEMM (R15-verified, ~58us): stage A once ----------------
// Block = 128m x 128n x ALL THREE matrices, BK=32. Per K-step: stage A (8KB) +
// Bq,Bk,Bv (8KB each); af[] read once from LDS and reused in-register for 3x16
// MFMAs. LDS traffic per mat per K64: 96KB -> 64KB; A global fetch /3. Grid 64
// mt x 8 panels = 512 blocks = EXACTLY 2 rounds at 2 resident blocks/CU (64KB
// LDS) — no dispatch tail. Swizzle for 64B rows: slot = hi ^ ((row>>1)&3)
// (bank-verified max 2-way = free); staging source inverse-permuted (rule 21).
// 2-phase dbuf schedule: prefetch t+1 issued after the barrier, drained at the
// NEXT barrier. V^T store KEY-PERMUTED (attn PV: key 16*hi+4*g+r -> pos 8*g+4*hi+r).
// ~888 TF-equivalent = this structure class's known ceiling; declared done.
__global__ __launch_bounds__(256, 2) void qkv_fused(
    const u16* __restrict__ xb,
    const u16* __restrict__ wtq, const u16* __restrict__ wtk, const u16* __restrict__ wtv,
    const float* __restrict__ bq, const float* __restrict__ bk, const float* __restrict__ bv,
    u16* __restrict__ qws, u16* __restrict__ kws, u16* __restrict__ vtws){
  __shared__ u16 sa[2][128 * 32];
  __shared__ u16 sq[2][128 * 32];
  __shared__ u16 sk[2][128 * 32];
  __shared__ u16 sv[2][128 * 32];

  const int id = blockIdx.x;              // 0..511
  const int local = id >> 3;              // 0..63 within XCD
  const int mt = (id & 7) * 8 + (local & 7);   // M-tile 0..63 (XCD stripe)
  const int panel = local >> 3;           // n-panel 0..7 (m-inner, L2-hot)
  const int m0 = mt * 128;
  const int n0 = panel * 128;
  const int tid = threadIdx.x;
  const int lane = tid & 63, w = tid >> 6;
  const int ln16 = lane & 15, hi = lane >> 4;
  const int wm = (w >> 1) * 64, wn = (w & 1) * 64;
  const int wb = tid & 192;               // wave-uniform chunk base

  f32x4 aq[4][4] = {}, ak[4][4] = {}, avv[4][4] = {};

  // staging: per buffer 512 chunks of 16B (128 rows x 4 slots), 2 passes x 256 thr.
  // chunk ci: row = ci>>2, slot = ci&3; source k-chunk = slot ^ ((row>>1)&3).
  #define STG(CUR, K0) { \
    _Pragma("unroll") \
    for(int p_ = 0; p_ < 2; p_++){ \
      int base_ = p_ * 256 + wb; \
      int ci_ = base_ + lane; \
      int row_ = ci_ >> 2, chs_ = (ci_ & 3) ^ ((row_ >> 1) & 3); \
      gload16(xb  + (size_t)(m0 + row_) * 1024 + (K0) + chs_ * 8, (char*)sa[CUR] + base_ * 16); \
      gload16(wtq + (size_t)(n0 + row_) * 1024 + (K0) + chs_ * 8, (char*)sq[CUR] + base_ * 16); \
      gload16(wtk + (size_t)(n0 + row_) * 1024 + (K0) + chs_ * 8, (char*)sk[CUR] + base_ * 16); \
      gload16(wtv + (size_t)(n0 + row_) * 1024 + (K0) + chs_ * 8, (char*)sv[CUR] + base_ * 16); \
    } }

  STG(0, 0)                               // stage K-step 0 -> buf 0

  #pragma unroll 1
  for(int kt = 0; kt < 32; kt++){
    const int cur = kt & 1;
    __syncthreads();               // drains vmcnt: buf[cur] ready; buf[cur^1] readers done

    if(kt + 1 < 32){               // prefetch K-step t+1 into buf^1 (drained at next barrier)
      const int k0n = (kt + 1) * 32;
      if(cur == 0){ STG(1, k0n) } else { STG(0, k0n) }
    }

    short8 af[4], bfr[4];
    #pragma unroll
    for(int i = 0; i < 4; i++){
      int ra = wm + i * 16 + ln16;
      af[i] = *(const short8*)((const char*)sa[cur] + ra * 64 + ((hi ^ ((ra >> 1) & 3)) << 4));
    }
    // ---- Q ----
    #pragma unroll
    for(int j = 0; j < 4; j++){
      int rb = wn + j * 16 + ln16;
      bfr[j] = *(const short8*)((const char*)sq[cur] + rb * 64 + ((hi ^ ((rb >> 1) & 3)) << 4));
    }
    __builtin_amdgcn_s_setprio(1);
    #pragma unroll
    for(int i = 0; i < 4; i++)
      #pragma unroll
      for(int j = 0; j < 4; j++)
        aq[i][j] = MFMA(af[i], bfr[j], aq[i][j]);
    __builtin_amdgcn_s_setprio(0);
    // ---- K ----
    #pragma unroll
    for(int j = 0; j < 4; j++){
      int rb = wn + j * 16 + ln16;
      bfr[j] = *(const short8*)((const char*)sk[cur] + rb * 64 + ((hi ^ ((rb >> 1) & 3)) << 4));
    }
    __builtin_amdgcn_s_setprio(1);
    #pragma unroll
    for(int i = 0; i < 4; i++)
      #pragma unroll
      for(int j = 0; j < 4; j++)
        ak[i][j] = MFMA(af[i], bfr[j], ak[i][j]);
    __builtin_amdgcn_s_setprio(0);
    // ---- V ----
    #pragma unroll
    for(int j = 0; j < 4; j++){
      int rb = wn + j * 16 + ln16;
      bfr[j] = *(const short8*)((const char*)sv[cur] + rb * 64 + ((hi ^ ((rb >> 1) & 3)) << 4));
    }
    __builtin_amdgcn_s_setprio(1);
    #pragma unroll
    for(int i = 0; i < 4; i++)
      #pragma unroll
      for(int j = 0; j < 4; j++)
        avv[i][j] = MFMA(af[i], bfr[j], avv[i][j]);
    __builtin_amdgcn_s_setprio(0);
  }
  #undef STG

  // epilogue: Q (scaled), K, V^T (key-permuted for attn's PV b128 reads)
  #pragma unroll
  for(int j = 0; j < 4; j++){
    int n = n0 + wn + j * 16 + ln16;
    float bq_ = bq[n], bk_ = bk[n], bv_ = bv[n];
    int h = n >> 6, d = n & 63;
    #pragma unroll
    for(int i = 0; i < 4; i++){
      int mb = m0 + wm + i * 16 + hi * 4;
      int b = mb >> 11, t = mb & 2047;
      int bh = b * NH + h;
      #pragma unroll
      for(int r = 0; r < 4; r++){
        qws[((size_t)bh * TT + t + r) * DK + d] = f2bf((aq[i][j][r] + bq_) * QSCALE);
        kws[((size_t)bh * TT + t + r) * DK + d] = f2bf(ak[i][j][r] + bk_);
      }
      ushort4 o4;
      o4.x = f2bf(avv[i][j][0] + bv_);
      o4.y = f2bf(avv[i][j][1] + bv_);
      o4.z = f2bf(avv[i][j][2] + bv_);
      o4.w = f2bf(avv[i][j][3] + bv_);
      int tp = (t & ~31) | (((t >> 2) & 3) << 3) | (((t >> 4) & 1) << 2);
      *(ushort4*)(vtws + ((size_t)bh * DK + d) * TT + tp) = o4;
    }
  }
}

// ---------------- flash attention: merged q-tile pair, shared K/V reads (R18) ----------------
// attn was measured AT the LDS-BW roofline for its read pattern (288KB/CU-iter
// at 128B/cyc = 2250cyc vs 2150 measured). The bytes are 8x wave-redundant AND
// 2x pass-redundant: the block's two q-tiles (x, 15-x) each re-read K/V. Merge:
// ONE loop over nktB = 32-2x k-tiles; tile A co-active while kti < nktA; kfr/av
// read ONCE per wave and MFMA'd into both tiles. Staging + LDS reads per block
// drop 34 -> 32-2x tiles (avg -26%). Balance (R2/R9 lesson) holds by SUM, not
// max: block ordering gives each CU blocks with complementary x (x, 7-x) ->
// 50 iters of LDS work per CU uniformly (dispatch-order heuristic; correctness
// is order-independent). 16 waves/CU kept (VGPR ~114 < 128). R16 fused-bias
// softmax per tile (C-init=-m fast path, defer-max, vector lv).
__global__ __launch_bounds__(512) void attn(
    const u16* __restrict__ qws, const u16* __restrict__ kws, const u16* __restrict__ vtws,
    float* __restrict__ out){
  __shared__ u16 kt[2][64 * 64];    // [buf][key][d]  swizzled
  __shared__ u16 vt[2][64 * 64];    // [buf][d][key-permuted]  swizzled

  const int id = blockIdx.x;
  const int xcd = id & 7;                      // XCD k owns bh in [8k,8k+8)
  const int j = id >> 3;                       // 0..63 within XCD (dispatch order)
  const int jj = j & 31, pass = j >> 5;        // CU pass 0/1 (2 blocks/CU)
  const int bh = xcd * 8 + (jj >> 2);
  const int ps = jj & 3;
  const int x = pass ? (7 - ps) : ps;          // CU gets x=ps then x=7-ps -> sum balanced
  const int qtA = x, qtB = 15 - x;             // short / long q-tile of the pair

  const int tid = threadIdx.x, lane = tid & 63, w = tid >> 6;   // w 0..7
  const int g = lane >> 4, ln = lane & 15;
  const int b = bh >> 4, h = bh & 15;
  const u16* kbase = kws + (size_t)bh * TT * DK;
  const u16* vbase = vtws + (size_t)bh * DK * TT;
  const int sbase = tid & 448;      // wave-uniform 16B-chunk base (HW adds lane*16)
  const int srow = tid >> 3;        // staging row 0..63
  const int schs = (tid & 7) ^ (srow & 7);     // inverse swizzle on the SOURCE

  const int qA = qtA * 128 + w * 16 + ln;      // this lane's q rows (both tiles)
  const int qB = qtB * 128 + w * 16 + ln;

  // Q fragments (B-operand; pre-scaled by QSCALE): k-slots d = g*8+j (+32)
  short8 qfA[2], qfB[2];
  {
    const u16* gq = qws + ((size_t)bh * TT + qA) * DK + g * 8;
    qfA[0] = *(const short8*)gq;
    qfA[1] = *(const short8*)(gq + 32);
    const u16* gq2 = qws + ((size_t)bh * TT + qB) * DK + g * 8;
    qfB[0] = *(const short8*)gq2;
    qfB[1] = *(const short8*)(gq2 + 32);
  }

  f32x4 oA[4] = {}, oB[4] = {};
  f32x4 lvA = {}, lvB = {};
  float mA = -INFINITY, mnegA = 0.f;
  float mB = -INFINITY, mnegB = 0.f;

  const int nktA = 2 * qtA + 2;
  const int nktB = 2 * qtB + 2;                // loop bound (>= nktA always)
  const int myNktA = nktA - (w < 4 ? 1 : 0);   // lower waves: last tile fully masked
  const int myNktB = nktB - (w < 4 ? 1 : 0);

  // stage k-tile 0 -> buf 0 (async DMA; 512 threads cover 64x64 in one pass)
  gload16(kbase + (size_t)srow * DK + schs * 8, (char*)kt[0] + sbase * 16);
  gload16(vbase + (size_t)srow * TT + schs * 8, (char*)vt[0] + sbase * 16);

  #pragma unroll 1
  for(int kti = 0; kti < nktB; kti++){
    const int cur = kti & 1;
    __syncthreads();               // drains vmcnt: buf[cur] ready; buf[cur^1] readers done

    // async-prefetch next tile straight into buf[cur^1] (drained at next barrier)
    if(kti + 1 < nktB){
      const int k0n = (kti + 1) * 64;
      gload16(kbase + (size_t)(k0n + srow) * DK + schs * 8, (char*)kt[cur ^ 1] + sbase * 16);
      gload16(vbase + (size_t)srow * TT + k0n + schs * 8, (char*)vt[cur ^ 1] + sbase * 16);
    }

    const bool doA = (kti < myNktA);   // wave-uniform
    const bool doB = (kti < myNktB);

    // S^T = K Q - m for BOTH tiles: kfr read ONCE, fed to both MFMAs
    f32x4 sA[4], sB[4];
    __builtin_amdgcn_s_setprio(1);
    #pragma unroll
    for(int i = 0; i < 4; i++){
      f32x4 cA = {mnegA, mnegA, mnegA, mnegA};
      f32x4 cB = {mnegB, mnegB, mnegB, mnegB};
      #pragma unroll
      for(int ks = 0; ks < 2; ks++){
        int rb = i * 16 + ln;
        int cb = ks * 64 + g * 16;
        short8 kfr = *(const short8*)((const char*)kt[cur] + rb * 128 + (cb ^ ((rb & 7) << 4)));
        if(doA) cA = MFMA(kfr, qfA[ks], cA);
        if(doB) cB = MFMA(kfr, qfB[ks], cB);
      }
      sA[i] = cA; sB[i] = cB;
    }
    __builtin_amdgcn_s_setprio(0);

    if(doA && kti == myNktA - 1){    // tile A diagonal mask
      const int k0 = kti * 64;
      #pragma unroll
      for(int i = 0; i < 4; i++)
        #pragma unroll
        for(int r = 0; r < 4; r++)
          if(k0 + i * 16 + g * 4 + r > qA) sA[i][r] = -INFINITY;
    }
    if(doB && kti == myNktB - 1){    // tile B diagonal mask
      const int k0 = kti * 64;
      #pragma unroll
      for(int i = 0; i < 4; i++)
        #pragma unroll
        for(int r = 0; r < 4; r++)
          if(k0 + i * 16 + g * 4 + r > qB) sB[i][r] = -INFINITY;
    }

    union PU { short8 s8; unsigned u[4]; };
    PU pbA[2], pbB[2];

    // ---- softmax + pack, tile A (wave-uniform guard) ----
    if(doA){
      float mx0 = fmaxf(fmaxf(fmaxf(sA[0][0], sA[0][1]), sA[0][2]), sA[0][3]);
      float mx1 = fmaxf(fmaxf(fmaxf(sA[1][0], sA[1][1]), sA[1][2]), sA[1][3]);
      float mx2 = fmaxf(fmaxf(fmaxf(sA[2][0], sA[2][1]), sA[2][2]), sA[2][3]);
      float mx3 = fmaxf(fmaxf(fmaxf(sA[3][0], sA[3][1]), sA[3][2]), sA[3][3]);
      float pmax = plmax(fmaxf(fmaxf(fmaxf(mx0, mx1), mx2), mx3));
      if(__all(pmax - mnegA <= mA + 8.f)){
        #pragma unroll
        for(int i = 0; i < 4; i++){
          f32x4 p;
          p[0] = EXP2(sA[i][0]); p[1] = EXP2(sA[i][1]);
          p[2] = EXP2(sA[i][2]); p[3] = EXP2(sA[i][3]);
          sA[i] = p; lvA += p;
        }
      } else {
        float mnew = fmaxf(mA, pmax - mnegA);
        float alpha = EXP2(mA - mnew);
        lvA *= alpha;
        #pragma unroll
        for(int i = 0; i < 4; i++) oA[i] *= alpha;
        float d = mnew + mnegA;
        mA = mnew; mnegA = -mnew;
        #pragma unroll
        for(int i = 0; i < 4; i++){
          f32x4 p;
          p[0] = EXP2(sA[i][0] - d); p[1] = EXP2(sA[i][1] - d);
          p[2] = EXP2(sA[i][2] - d); p[3] = EXP2(sA[i][3] - d);
          sA[i] = p; lvA += p;
        }
      }
      #pragma unroll
      for(int ks = 0; ks < 2; ks++){
        pbA[ks].u[0] = cvtpk(sA[2*ks][0],   sA[2*ks][1]);
        pbA[ks].u[1] = cvtpk(sA[2*ks][2],   sA[2*ks][3]);
        pbA[ks].u[2] = cvtpk(sA[2*ks+1][0], sA[2*ks+1][1]);
        pbA[ks].u[3] = cvtpk(sA[2*ks+1][2], sA[2*ks+1][3]);
      }
    }

    // ---- softmax + pack, tile B ----
    if(doB){
      float mx0 = fmaxf(fmaxf(fmaxf(sB[0][0], sB[0][1]), sB[0][2]), sB[0][3]);
      float mx1 = fmaxf(fmaxf(fmaxf(sB[1][0], sB[1][1]), sB[1][2]), sB[1][3]);
      float mx2 = fmaxf(fmaxf(fmaxf(sB[2][0], sB[2][1]), sB[2][2]), sB[2][3]);
      float mx3 = fmaxf(fmaxf(fmaxf(sB[3][0], sB[3][1]), sB[3][2]), sB[3][3]);
      float pmax = plmax(fmaxf(fmaxf(fmaxf(mx0, mx1), mx2), mx3));
      if(__all(pmax - mnegB <= mB + 8.f)){
        #pragma unroll
        for(int i = 0; i < 4; i++){
          f32x4 p;
          p[0] = EXP2(sB[i][0]); p[1] = EXP2(sB[i][1]);
          p[2] = EXP2(sB[i][2]); p[3] = EXP2(sB[i][3]);
          sB[i] = p; lvB += p;
        }
      } else {
        float mnew = fmaxf(mB, pmax - mnegB);
        float alpha = EXP2(mB - mnew);
        lvB *= alpha;
        #pragma unroll
        for(int i = 0; i < 4; i++) oB[i] *= alpha;
        float d = mnew + mnegB;
        mB = mnew; mnegB = -mnew;
        #pragma unroll
        for(int i = 0; i < 4; i++){
          f32x4 p;
          p[0] = EXP2(sB[i][0] - d); p[1] = EXP2(sB[i][1] - d);
          p[2] = EXP2(sB[i][2] - d); p[3] = EXP2(sB[i][3] - d);
          sB[i] = p; lvB += p;
        }
      }
      #pragma unroll
      for(int ks = 0; ks < 2; ks++){
        pbB[ks].u[0] = cvtpk(sB[2*ks][0],   sB[2*ks][1]);
        pbB[ks].u[1] = cvtpk(sB[2*ks][2],   sB[2*ks][3]);
        pbB[ks].u[2] = cvtpk(sB[2*ks+1][0], sB[2*ks+1][1]);
        pbB[ks].u[3] = cvtpk(sB[2*ks+1][2], sB[2*ks+1][3]);
      }
    }

    // O^T += V^T P^T for BOTH tiles: av read ONCE (key-permuted vt, conflict-free)
    __builtin_amdgcn_s_setprio(1);
    #pragma unroll
    for(int i = 0; i < 4; i++){
      int dr = i * 16 + ln;
      const char* vrow = (const char*)vt[cur] + dr * 128;
      int sw = (dr & 7) << 4;
      #pragma unroll
      for(int ks = 0; ks < 2; ks++){
        short8 av = *(const short8*)(vrow + ((64 * ks + g * 16) ^ sw));
        if(doA) oA[i] = MFMA(av, pbA[ks].s8, oA[i]);
        if(doB) oB[i] = MFMA(av, pbB[ks].s8, oB[i]);
      }
    }
    __builtin_amdgcn_s_setprio(0);
  }

  // epilogue x2: deferred l reduces, then float4 stores (d = i*16 + g*4 + r)
  float lA = (lvA[0] + lvA[1]) + (lvA[2] + lvA[3]);
  float lB = (lvB[0] + lvB[1]) + (lvB[2] + lvB[3]);
  lA = plsum(lA);
  lB = plsum(lB);
  float invA = 1.0f / lA, invB = 1.0f / lB;
  float* orowA = out + ((size_t)(b * TT + qA)) * DM + h * 64 + g * 4;
  float* orowB = out + ((size_t)(b * TT + qB)) * DM + h * 64 + g * 4;
  #pragma unroll
  for(int i = 0; i < 4; i++){
    float4 v4;
    v4.x = oA[i][0] * invA; v4.y = oA[i][1] * invA;
    v4.z = oA[i][2] * invA; v4.w = oA[i][3] * invA;
    *(float4*)(orowA + i * 16) = v4;
    float4 v5;
    v5.x = oB[i][0] * invB; v5.y = oB[i][1] * invB;
    v5.z = oB[i][2] * invB; v5.w = oB[i][3] * invB;
    *(float4*)(orowB + i * 16) = v5;
  }
}

extern "C" void kernel_launch(void* const* d_in, const int* in_sizes, int n_in,
                              void* d_out, int out_size, void* d_ws, size_t ws_size,
                              hipStream_t stream){
  const float* x  = (const float*)d_in[0];
  const float* Wq = (const float*)d_in[1];
  const float* bq = (const float*)d_in[2];
  const float* Wk = (const float*)d_in[3];
  const float* bk = (const float*)d_in[4];
  const float* Wv = (const float*)d_in[5];
  const float* bv = (const float*)d_in[6];
  float* out = (float*)d_out;

  char* ws = (char*)d_ws;
  u16* xb   = (u16*)(ws);                       // 16 MB  x bf16 (M,K)
  u16* wtq  = (u16*)(ws + (16u << 20));         //  2 MB  Wq^T bf16 (N,K)
  u16* wtk  = (u16*)(ws + (18u << 20));
  u16* wtv  = (u16*)(ws + (20u << 20));
  u16* qws  = (u16*)(ws + (22u << 20));         // 16 MB  Q (BH,T,DK) bf16 (pre-scaled)
  u16* kws  = (u16*)(ws + (38u << 20));         // 16 MB  K (BH,T,DK) bf16
  u16* vtws = (u16*)(ws + (54u << 20));         // 16 MB  V^T (BH,DK,T) bf16, key-permuted

  prep<<<dim3(8192 + 3072), dim3(256), 0, stream>>>(x, xb, Wq, Wk, Wv, wtq, wtk, wtv);
  qkv_fused<<<dim3(512), dim3(256), 0, stream>>>(xb, wtq, wtk, wtv, bq, bk, bv, qws, kws, vtws);
  attn<<<dim3(512), dim3(512), 0, stream>>>(qws, kws, vtws, out);
}

// Round 19
// 129.354 us; speedup vs baseline: 4.5633x; 4.5633x over previous
//
#include <hip/hip_runtime.h>
#include <hip/hip_bf16.h>

#define DM 1024
#define NH 16
#define DK 64
#define TT 2048
#define NBATCH 4
#define BT 8192   // NBATCH*TT

typedef __attribute__((ext_vector_type(8))) short short8;
typedef __attribute__((ext_vector_type(4))) float f32x4;
typedef unsigned short u16;

#define MFMA(a,b,c) __builtin_amdgcn_mfma_f32_16x16x32_bf16((a),(b),(c),0,0,0)

// 1/sqrt(64) * log2(e): folded into Q so attn softmax can use exp2 directly
#define QSCALE 0.18033688011112684f

// raw v_exp_f32 (flush-denorm fine for softmax), skips OCML fixup code
#define EXP2(x) __builtin_amdgcn_exp2f(x)

__device__ __forceinline__ u16 f2bf(float f){
  union { float f; unsigned u; } v; v.f = f;
  return (u16)((v.u + 0x7fffu + ((v.u >> 16) & 1u)) >> 16);
}

__device__ __forceinline__ unsigned cvtpk(float lo, float hi){
  unsigned r;
  asm("v_cvt_pk_bf16_f32 %0, %1, %2" : "=v"(r) : "v"(lo), "v"(hi));
  return r;
}

// async global->LDS DMA, 16B/lane. LDS dest must be wave-uniform base (+lane*16).
__device__ __forceinline__ void gload16(const void* g, void* l){
  __builtin_amdgcn_global_load_lds((__attribute__((address_space(1))) void*)(g),
                                   (__attribute__((address_space(3))) void*)(l), 16, 0, 0);
}

// cross-lane reduce over the 4 16-lane groups (lane ^16, ^32): pure-VALU permlanes
__device__ __forceinline__ float plmax(float x){
#if __has_builtin(__builtin_amdgcn_permlane16_swap) && __has_builtin(__builtin_amdgcn_permlane32_swap)
  auto r = __builtin_amdgcn_permlane16_swap(__float_as_uint(x), __float_as_uint(x), false, false);
  x = fmaxf(__uint_as_float(r[0]), __uint_as_float(r[1]));
  auto r2 = __builtin_amdgcn_permlane32_swap(__float_as_uint(x), __float_as_uint(x), false, false);
  x = fmaxf(__uint_as_float(r2[0]), __uint_as_float(r2[1]));
#else
  x = fmaxf(x, __shfl_xor(x, 16, 64));
  x = fmaxf(x, __shfl_xor(x, 32, 64));
#endif
  return x;
}

__device__ __forceinline__ float plsum(float x){
#if __has_builtin(__builtin_amdgcn_permlane16_swap) && __has_builtin(__builtin_amdgcn_permlane32_swap)
  auto r = __builtin_amdgcn_permlane16_swap(__float_as_uint(x), __float_as_uint(x), false, false);
  x = __uint_as_float(r[0]) + __uint_as_float(r[1]);
  auto r2 = __builtin_amdgcn_permlane32_swap(__float_as_uint(x), __float_as_uint(x), false, false);
  x = __uint_as_float(r2[0]) + __uint_as_float(r2[1]);
#else
  x = x + __shfl_xor(x, 16, 64);
  x = x + __shfl_xor(x, 32, 64);
#endif
  return x;
}

// ---------------- prep: x fp32->bf16  +  W (K,N) fp32 -> wt (N,K) bf16 ----------------
// merged single launch (block-uniform branch): blocks [0,8192) convert x,
// blocks [8192, 8192+3072) transpose+convert the three weight matrices.
__global__ __launch_bounds__(256) void prep(
    const float* __restrict__ x, u16* __restrict__ xb,
    const float* __restrict__ Wq, const float* __restrict__ Wk, const float* __restrict__ Wv,
    u16* __restrict__ wtq, u16* __restrict__ wtk, u16* __restrict__ wtv){
  __shared__ float tile[32][33];
  const int id = blockIdx.x;
  if(id < 8192){
    int i = (id * 256 + threadIdx.x) * 4;
    float4 v = *(const float4*)(x + i);
    ushort4 o; o.x = f2bf(v.x); o.y = f2bf(v.y); o.z = f2bf(v.z); o.w = f2bf(v.w);
    *(ushort4*)(xb + i) = o;
  } else {
    int r3 = id - 8192;                 // 0..3071
    int z = r3 >> 10;                   // 0..2
    int rem = r3 & 1023;
    int bx = rem & 31, by = rem >> 5;
    const float* W = (z == 0) ? Wq : (z == 1) ? Wk : Wv;
    u16* wt = (z == 0) ? wtq : (z == 1) ? wtk : wtv;
    int k0 = bx * 32, n0 = by * 32;
    int tx = threadIdx.x & 31, ty = threadIdx.x >> 5;
    #pragma unroll
    for(int r = ty; r < 32; r += 8)
      tile[r][tx] = W[(size_t)(k0 + r) * DM + n0 + tx];
    __syncthreads();
    #pragma unroll
    for(int r = ty; r < 32; r += 8)
      wt[(size_t)(n0 + r) * DM + k0 + tx] = f2bf(tile[tx][r]);
  }
}

// ---------------- FUSED QKV projection GEMM (R15-verified, ~58us): stage A once ----------------
// Block = 128m x 128n x ALL THREE matrices, BK=32. Per K-step: stage A (8KB) +
// Bq,Bk,Bv (8KB each); af[] read once from LDS and reused in-register for 3x16
// MFMAs. LDS traffic per mat per K64: 96KB -> 64KB; A global fetch /3. Grid 64
// mt x 8 panels = 512 blocks = EXACTLY 2 rounds at 2 resident blocks/CU (64KB
// LDS) — no dispatch tail. Swizzle for 64B rows: slot = hi ^ ((row>>1)&3)
// (bank-verified max 2-way = free); staging source inverse-permuted (rule 21).
// 2-phase dbuf schedule: prefetch t+1 issued after the barrier, drained at the
// NEXT barrier. V^T store KEY-PERMUTED (attn PV: key 16*hi+4*g+r -> pos 8*g+4*hi+r).
// ~888 TF-equivalent = this structure class's known ceiling; declared done.
__global__ __launch_bounds__(256, 2) void qkv_fused(
    const u16* __restrict__ xb,
    const u16* __restrict__ wtq, const u16* __restrict__ wtk, const u16* __restrict__ wtv,
    const float* __restrict__ bq, const float* __restrict__ bk, const float* __restrict__ bv,
    u16* __restrict__ qws, u16* __restrict__ kws, u16* __restrict__ vtws){
  __shared__ u16 sa[2][128 * 32];
  __shared__ u16 sq[2][128 * 32];
  __shared__ u16 sk[2][128 * 32];
  __shared__ u16 sv[2][128 * 32];

  const int id = blockIdx.x;              // 0..511
  const int local = id >> 3;              // 0..63 within XCD
  const int mt = (id & 7) * 8 + (local & 7);   // M-tile 0..63 (XCD stripe)
  const int panel = local >> 3;           // n-panel 0..7 (m-inner, L2-hot)
  const int m0 = mt * 128;
  const int n0 = panel * 128;
  const int tid = threadIdx.x;
  const int lane = tid & 63, w = tid >> 6;
  const int ln16 = lane & 15, hi = lane >> 4;
  const int wm = (w >> 1) * 64, wn = (w & 1) * 64;
  const int wb = tid & 192;               // wave-uniform chunk base

  f32x4 aq[4][4] = {}, ak[4][4] = {}, avv[4][4] = {};

  // staging: per buffer 512 chunks of 16B (128 rows x 4 slots), 2 passes x 256 thr.
  // chunk ci: row = ci>>2, slot = ci&3; source k-chunk = slot ^ ((row>>1)&3).
  #define STG(CUR, K0) { \
    _Pragma("unroll") \
    for(int p_ = 0; p_ < 2; p_++){ \
      int base_ = p_ * 256 + wb; \
      int ci_ = base_ + lane; \
      int row_ = ci_ >> 2, chs_ = (ci_ & 3) ^ ((row_ >> 1) & 3); \
      gload16(xb  + (size_t)(m0 + row_) * 1024 + (K0) + chs_ * 8, (char*)sa[CUR] + base_ * 16); \
      gload16(wtq + (size_t)(n0 + row_) * 1024 + (K0) + chs_ * 8, (char*)sq[CUR] + base_ * 16); \
      gload16(wtk + (size_t)(n0 + row_) * 1024 + (K0) + chs_ * 8, (char*)sk[CUR] + base_ * 16); \
      gload16(wtv + (size_t)(n0 + row_) * 1024 + (K0) + chs_ * 8, (char*)sv[CUR] + base_ * 16); \
    } }

  STG(0, 0)                               // stage K-step 0 -> buf 0

  #pragma unroll 1
  for(int kt = 0; kt < 32; kt++){
    const int cur = kt & 1;
    __syncthreads();               // drains vmcnt: buf[cur] ready; buf[cur^1] readers done

    if(kt + 1 < 32){               // prefetch K-step t+1 into buf^1 (drained at next barrier)
      const int k0n = (kt + 1) * 32;
      if(cur == 0){ STG(1, k0n) } else { STG(0, k0n) }
    }

    short8 af[4], bfr[4];
    #pragma unroll
    for(int i = 0; i < 4; i++){
      int ra = wm + i * 16 + ln16;
      af[i] = *(const short8*)((const char*)sa[cur] + ra * 64 + ((hi ^ ((ra >> 1) & 3)) << 4));
    }
    // ---- Q ----
    #pragma unroll
    for(int j = 0; j < 4; j++){
      int rb = wn + j * 16 + ln16;
      bfr[j] = *(const short8*)((const char*)sq[cur] + rb * 64 + ((hi ^ ((rb >> 1) & 3)) << 4));
    }
    __builtin_amdgcn_s_setprio(1);
    #pragma unroll
    for(int i = 0; i < 4; i++)
      #pragma unroll
      for(int j = 0; j < 4; j++)
        aq[i][j] = MFMA(af[i], bfr[j], aq[i][j]);
    __builtin_amdgcn_s_setprio(0);
    // ---- K ----
    #pragma unroll
    for(int j = 0; j < 4; j++){
      int rb = wn + j * 16 + ln16;
      bfr[j] = *(const short8*)((const char*)sk[cur] + rb * 64 + ((hi ^ ((rb >> 1) & 3)) << 4));
    }
    __builtin_amdgcn_s_setprio(1);
    #pragma unroll
    for(int i = 0; i < 4; i++)
      #pragma unroll
      for(int j = 0; j < 4; j++)
        ak[i][j] = MFMA(af[i], bfr[j], ak[i][j]);
    __builtin_amdgcn_s_setprio(0);
    // ---- V ----
    #pragma unroll
    for(int j = 0; j < 4; j++){
      int rb = wn + j * 16 + ln16;
      bfr[j] = *(const short8*)((const char*)sv[cur] + rb * 64 + ((hi ^ ((rb >> 1) & 3)) << 4));
    }
    __builtin_amdgcn_s_setprio(1);
    #pragma unroll
    for(int i = 0; i < 4; i++)
      #pragma unroll
      for(int j = 0; j < 4; j++)
        avv[i][j] = MFMA(af[i], bfr[j], avv[i][j]);
    __builtin_amdgcn_s_setprio(0);
  }
  #undef STG

  // epilogue: Q (scaled), K, V^T (key-permuted for attn's PV b128 reads)
  #pragma unroll
  for(int j = 0; j < 4; j++){
    int n = n0 + wn + j * 16 + ln16;
    float bq_ = bq[n], bk_ = bk[n], bv_ = bv[n];
    int h = n >> 6, d = n & 63;
    #pragma unroll
    for(int i = 0; i < 4; i++){
      int mb = m0 + wm + i * 16 + hi * 4;
      int b = mb >> 11, t = mb & 2047;
      int bh = b * NH + h;
      #pragma unroll
      for(int r = 0; r < 4; r++){
        qws[((size_t)bh * TT + t + r) * DK + d] = f2bf((aq[i][j][r] + bq_) * QSCALE);
        kws[((size_t)bh * TT + t + r) * DK + d] = f2bf(ak[i][j][r] + bk_);
      }
      ushort4 o4;
      o4.x = f2bf(avv[i][j][0] + bv_);
      o4.y = f2bf(avv[i][j][1] + bv_);
      o4.z = f2bf(avv[i][j][2] + bv_);
      o4.w = f2bf(avv[i][j][3] + bv_);
      int tp = (t & ~31) | (((t >> 2) & 3) << 3) | (((t >> 4) & 1) << 2);
      *(ushort4*)(vtws + ((size_t)bh * DK + d) * TT + tp) = o4;
    }
  }
}

// ---------------- flash attention (R16-verified best, 62us): 8-wave + fused-bias softmax ----------------
// Grid 512, XCD-bijective, paired (x,15-x) -> exactly 34 iters/block, 16 waves/CU,
// VGPR 60 (< 64 cliff), conflict-free PV (key-permuted V^T). C-init=-m softmax:
// fast path p = exp2(s) with no per-score subtract; rescale path ~1/block.
// Measured AT the LDS-BW roofline for this read pattern: 288KB/CU-iter at
// 128 B/cyc = 2250 cyc model vs 2150 measured. Byte-reduction variants all
// closed: 32x32 core (R8, wave-count regime), dual-subtile (R9, balance),
// shared-read merged pair (R18, 128-VGPR spill -> 1.4GB scratch traffic).
__global__ __launch_bounds__(512) void attn(
    const u16* __restrict__ qws, const u16* __restrict__ kws, const u16* __restrict__ vtws,
    float* __restrict__ out){
  __shared__ u16 kt[2][64 * 64];    // [buf][key][d]  swizzled
  __shared__ u16 vt[2][64 * 64];    // [buf][d][key-permuted]  swizzled

  const int id = blockIdx.x;
  const int swz = (id & 7) * 64 + (id >> 3);   // bijective (512 % 8 == 0)
  const int qx = swz & 7;                      // pair index 0..7
  const int bh = swz >> 3;

  const int tid = threadIdx.x, lane = tid & 63, w = tid >> 6;   // w 0..7
  const int g = lane >> 4, ln = lane & 15;
  const int b = bh >> 4, h = bh & 15;
  const u16* kbase = kws + (size_t)bh * TT * DK;
  const u16* vbase = vtws + (size_t)bh * DK * TT;
  const int sbase = tid & 448;      // wave-uniform 16B-chunk base (HW adds lane*16)
  const int srow = tid >> 3;        // staging row 0..63
  const int schs = (tid & 7) ^ (srow & 7);     // inverse swizzle on the SOURCE

  #pragma unroll 1
  for(int qi = 0; qi < 2; qi++){
    const int qt = qi ? (15 - qx) : qx;        // 128-row q-tile 0..15
    const int q = qt * 128 + w * 16 + ln;      // this lane's q row

    // Q fragment (B-operand; pre-scaled by QSCALE): k-slots d = g*8+j (+32)
    short8 qf[2];
    {
      const u16* gq = qws + ((size_t)bh * TT + q) * DK + g * 8;
      qf[0] = *(const short8*)gq;
      qf[1] = *(const short8*)(gq + 32);
    }

    f32x4 o[4] = {};                 // O^T frags: o[i][r] = O^T[d=i*16+g*4+r][q]
    f32x4 lv = {};                   // per-lane vector partial sum (epilogue-reduced)
    float m = -INFINITY, mneg = 0.f; // running max; -m is the MFMA C-in bias

    const int nkt = 2 * qt + 2;            // block-level 64-key tiles
    const int myNkt = nkt - (w < 4 ? 1 : 0);  // lower waves: last tile fully masked

    __syncthreads();                 // prev q-tile readers done; no DMAs outstanding
    // stage k-tile 0 -> buf 0 (async DMA; 512 threads cover 64x64 in one pass)
    gload16(kbase + (size_t)srow * DK + schs * 8, (char*)kt[0] + sbase * 16);
    gload16(vbase + (size_t)srow * TT + schs * 8, (char*)vt[0] + sbase * 16);

    #pragma unroll 1
    for(int kti = 0; kti < nkt; kti++){
      const int cur = kti & 1;
      __syncthreads();               // drains vmcnt: buf[cur] ready; buf[cur^1] readers done

      // async-prefetch next tile straight into buf[cur^1] (drained at next barrier)
      if(kti + 1 < nkt){
        const int k0n = (kti + 1) * 64;
        gload16(kbase + (size_t)(k0n + srow) * DK + schs * 8, (char*)kt[cur ^ 1] + sbase * 16);
        gload16(vbase + (size_t)srow * TT + k0n + schs * 8, (char*)vt[cur ^ 1] + sbase * 16);
      }

      if(kti < myNkt){
        // S^T = K Q - m : s[i][r] = S[key = k0+i*16+g*4+r][q] - m  (bias via C-in)
        f32x4 s[4];
        __builtin_amdgcn_s_setprio(1);
        #pragma unroll
        for(int i = 0; i < 4; i++){
          f32x4 c = {mneg, mneg, mneg, mneg};
          #pragma unroll
          for(int ks = 0; ks < 2; ks++){
            int rb = i * 16 + ln;
            int cb = ks * 64 + g * 16;
            short8 kfr = *(const short8*)((const char*)kt[cur] + rb * 128 + (cb ^ ((rb & 7) << 4)));
            c = MFMA(kfr, qf[ks], c);
          }
          s[i] = c;
        }
        __builtin_amdgcn_s_setprio(0);

        if(kti == myNkt - 1){          // causal mask (this wave's diagonal tile)
          const int k0 = kti * 64;
          #pragma unroll
          for(int i = 0; i < 4; i++)
            #pragma unroll
            for(int r = 0; r < 4; r++)
              if(k0 + i * 16 + g * 4 + r > q) s[i][r] = -INFINITY;
        }

        // biased row max: 4-long chains fuse to v_max3; cross-group permlanes
        float mx0 = fmaxf(fmaxf(fmaxf(s[0][0], s[0][1]), s[0][2]), s[0][3]);
        float mx1 = fmaxf(fmaxf(fmaxf(s[1][0], s[1][1]), s[1][2]), s[1][3]);
        float mx2 = fmaxf(fmaxf(fmaxf(s[2][0], s[2][1]), s[2][2]), s[2][3]);
        float mx3 = fmaxf(fmaxf(fmaxf(s[3][0], s[3][1]), s[3][2]), s[3][3]);
        float pmax = fmaxf(fmaxf(fmaxf(mx0, mx1), mx2), mx3);
        pmax = plmax(pmax);            // true tile max = pmax - mneg (per q-row)

        if(__all(pmax - mneg <= m + 8.f)){
          // fast path (defer-max): NO subtract — s is already score - m
          #pragma unroll
          for(int i = 0; i < 4; i++){
            f32x4 p;
            p[0] = EXP2(s[i][0]); p[1] = EXP2(s[i][1]);
            p[2] = EXP2(s[i][2]); p[3] = EXP2(s[i][3]);
            s[i] = p; lv += p;
          }
        } else {
          // rescale path (first tile + rare growth)
          float mnew = fmaxf(m, pmax - mneg);
          float alpha = EXP2(m - mnew);          // exp2(-inf)=0 on first tile
          lv *= alpha;
          #pragma unroll
          for(int i = 0; i < 4; i++) o[i] *= alpha;
          float d = mnew + mneg;                 // s - d = score - mnew
          m = mnew; mneg = -mnew;
          #pragma unroll
          for(int i = 0; i < 4; i++){
            f32x4 p;
            p[0] = EXP2(s[i][0] - d); p[1] = EXP2(s[i][1] - d);
            p[2] = EXP2(s[i][2] - d); p[3] = EXP2(s[i][3] - d);
            s[i] = p; lv += p;
          }
        }

        // pack P to bf16 B-frags in-register: pb[ks] reg j holds key kappa(g,j)+32ks
        union PU { short8 s8; unsigned w[4]; };
        PU pb[2];
        #pragma unroll
        for(int ks = 0; ks < 2; ks++){
          pb[ks].w[0] = cvtpk(s[2*ks][0],   s[2*ks][1]);
          pb[ks].w[1] = cvtpk(s[2*ks][2],   s[2*ks][3]);
          pb[ks].w[2] = cvtpk(s[2*ks+1][0], s[2*ks+1][1]);
          pb[ks].w[3] = cvtpk(s[2*ks+1][2], s[2*ks+1][3]);
        }

        // O^T += V^T P^T : key-permuted vt makes each A-frag ONE swizzled b128 read
        __builtin_amdgcn_s_setprio(1);
        #pragma unroll
        for(int i = 0; i < 4; i++){
          int dr = i * 16 + ln;
          const char* vrow = (const char*)vt[cur] + dr * 128;
          int sw = (dr & 7) << 4;
          #pragma unroll
          for(int ks = 0; ks < 2; ks++){
            short8 av = *(const short8*)(vrow + ((64 * ks + g * 16) ^ sw));
            o[i] = MFMA(av, pb[ks].s8, o[i]);
          }
        }
        __builtin_amdgcn_s_setprio(0);
      }
    }

    // epilogue: deferred l reduce, then out (B,T,DM) fp32, float4 stores
    float l = (lv[0] + lv[1]) + (lv[2] + lv[3]);
    l = plsum(l);
    float inv = 1.0f / l;
    float* orow = out + ((size_t)(b * TT + q)) * DM + h * 64 + g * 4;
    #pragma unroll
    for(int i = 0; i < 4; i++){
      float4 v4;
      v4.x = o[i][0] * inv; v4.y = o[i][1] * inv;
      v4.z = o[i][2] * inv; v4.w = o[i][3] * inv;
      *(float4*)(orow + i * 16) = v4;
    }
  }
}

extern "C" void kernel_launch(void* const* d_in, const int* in_sizes, int n_in,
                              void* d_out, int out_size, void* d_ws, size_t ws_size,
                              hipStream_t stream){
  const float* x  = (const float*)d_in[0];
  const float* Wq = (const float*)d_in[1];
  const float* bq = (const float*)d_in[2];
  const float* Wk = (const float*)d_in[3];
  const float* bk = (const float*)d_in[4];
  const float* Wv = (const float*)d_in[5];
  const float* bv = (const float*)d_in[6];
  float* out = (float*)d_out;

  char* ws = (char*)d_ws;
  u16* xb   = (u16*)(ws);                       // 16 MB  x bf16 (M,K)
  u16* wtq  = (u16*)(ws + (16u << 20));         //  2 MB  Wq^T bf16 (N,K)
  u16* wtk  = (u16*)(ws + (18u << 20));
  u16* wtv  = (u16*)(ws + (20u << 20));
  u16* qws  = (u16*)(ws + (22u << 20));         // 16 MB  Q (BH,T,DK) bf16 (pre-scaled)
  u16* kws  = (u16*)(ws + (38u << 20));         // 16 MB  K (BH,T,DK) bf16
  u16* vtws = (u16*)(ws + (54u << 20));         // 16 MB  V^T (BH,DK,T) bf16, key-permuted

  prep<<<dim3(8192 + 3072), dim3(256), 0, stream>>>(x, xb, Wq, Wk, Wv, wtq, wtk, wtv);
  qkv_fused<<<dim3(512), dim3(256), 0, stream>>>(xb, wtq, wtk, wtv, bq, bk, bv, qws, kws, vtws);
  attn<<<dim3(512), dim3(512), 0, stream>>>(qws, kws, vtws, out);
}